// Round 1
// baseline (122.348 us; speedup 1.0000x reference)
//
#include <hip/hip_runtime.h>
#include <hip/hip_bf16.h>

typedef __attribute__((ext_vector_type(8))) short bf16x8;
typedef __attribute__((ext_vector_type(4))) float f32x4;

#define B_ 8
#define S_ 1024
#define R_ 16384
#define H_ 128
#define D_ 256     // input dim = 2H
#define F_ 384     // inter dim

__device__ __forceinline__ unsigned short f2bf(float x) {
    unsigned int u = __float_as_uint(x);
    u += 0x7FFF + ((u >> 16) & 1);   // round-to-nearest-even
    return (unsigned short)(u >> 16);
}

__global__ __launch_bounds__(256) void k_cvt_span(const float* __restrict__ in,
                                                  unsigned short* __restrict__ out) {
    int i = blockIdx.x * 256 + threadIdx.x;   // 262144 threads, 4 elems each
    float4 v = reinterpret_cast<const float4*>(in)[i];
    ushort4 o;
    o.x = f2bf(v.x); o.y = f2bf(v.y); o.z = f2bf(v.z); o.w = f2bf(v.w);
    reinterpret_cast<ushort4*>(out)[i] = o;
}

__global__ __launch_bounds__(256) void k_t_w1(const float* __restrict__ W1,
                                              unsigned short* __restrict__ W1T) {
    int i = blockIdx.x * 256 + threadIdx.x;   // 98304: W1T[f][d] = W1[d][f]
    int d = i & 255, f = i >> 8;
    W1T[i] = f2bf(W1[d * F_ + f]);
}

__global__ __launch_bounds__(256) void k_t_w2(const float* __restrict__ W2,
                                              unsigned short* __restrict__ W2T) {
    int i = blockIdx.x * 256 + threadIdx.x;   // 49152: W2T[o][f] = W2[f][o]
    int o = i / F_, f = i - o * F_;
    W2T[i] = f2bf(W2[f * H_ + o]);
}

// 64 rows per block, 4 waves. LDS: A tile 32 KiB + h tile 48 KiB, both XOR-swizzled.
__global__ __launch_bounds__(256, 2) void k_main(
    const unsigned short* __restrict__ spanbf,
    const int* __restrict__ rel_ids,
    const unsigned short* __restrict__ W1T,
    const float* __restrict__ b1,
    const unsigned short* __restrict__ W2T,
    const float* __restrict__ b2,
    float* __restrict__ out)
{
    extern __shared__ char smem[];
    char* sA = smem;              // [64][256] bf16, row stride 512 B, swizzled
    char* sH = smem + 32768;      // [64][384] bf16, row stride 768 B, swizzled

    const int tid = threadIdx.x;
    const int blk = blockIdx.x;           // 0..2047
    const int m0  = blk << 6;             // 64 rows per block
    const int b   = m0 >> 14;
    const int r0  = m0 & 16383;

    // ---------------- stage A: gathered rel_reps (bf16) ----------------
    {
        const int m = tid >> 2;               // 0..63 local row
        const int q = tid & 3;                // quarter of the 256-dim row
        const int2 ids = reinterpret_cast<const int2*>(rel_ids)[(b << 14) + r0 + m];
        const int idx = (q < 2) ? ids.x : ids.y;
        const uint4* src = reinterpret_cast<const uint4*>(
            spanbf + (((b << 10) + idx) << 7) + ((q & 1) << 6));
        const int base = m * 512 + q * 128;
        const int swz = (m & 7) << 4;
        #pragma unroll
        for (int j = 0; j < 8; ++j) {
            uint4 v = src[j];
            *reinterpret_cast<uint4*>(sA + ((base + j * 16) ^ swz)) = v;
        }
    }
    __syncthreads();

    const int w  = tid >> 6;   // wave 0..3
    const int l  = tid & 63;
    const int lr = l & 15;
    const int lg = l >> 4;

    // ---------------- layer 1: h = relu(A @ W1 + b1), wave w owns f in [w*96, w*96+96) ----
    #pragma unroll 1
    for (int pair = 0; pair < 2; ++pair) {
        bf16x8 Af[2][8];
        #pragma unroll
        for (int mt = 0; mt < 2; ++mt) {
            const int m = ((pair << 1) + mt) * 16 + lr;
            const int swz = (m & 7) << 4;
            #pragma unroll
            for (int kt = 0; kt < 8; ++kt) {
                Af[mt][kt] = *reinterpret_cast<const bf16x8*>(
                    sA + ((m * 512 + kt * 64 + lg * 16) ^ swz));
            }
        }
        f32x4 acc[6][2];
        #pragma unroll
        for (int ft = 0; ft < 6; ++ft) {
            acc[ft][0] = {0.f, 0.f, 0.f, 0.f};
            acc[ft][1] = {0.f, 0.f, 0.f, 0.f};
        }
        #pragma unroll
        for (int ft = 0; ft < 6; ++ft) {
            const unsigned short* wr = W1T + (w * 96 + ft * 16 + lr) * 256 + lg * 8;
            #pragma unroll
            for (int kt = 0; kt < 8; ++kt) {
                bf16x8 Bf = *reinterpret_cast<const bf16x8*>(wr + kt * 32);
                acc[ft][0] = __builtin_amdgcn_mfma_f32_16x16x32_bf16(Af[0][kt], Bf, acc[ft][0], 0, 0, 0);
                acc[ft][1] = __builtin_amdgcn_mfma_f32_16x16x32_bf16(Af[1][kt], Bf, acc[ft][1], 0, 0, 0);
            }
        }
        // epilogue: bias + relu + store h (bf16) into LDS
        #pragma unroll
        for (int ft = 0; ft < 6; ++ft) {
            const int f = w * 96 + ft * 16 + lr;
            const float bias = b1[f];
            #pragma unroll
            for (int mt = 0; mt < 2; ++mt) {
                #pragma unroll
                for (int r = 0; r < 4; ++r) {
                    float v = fmaxf(acc[ft][mt][r] + bias, 0.0f);
                    const int m = ((pair << 1) + mt) * 16 + (lg << 2) + r;
                    *reinterpret_cast<unsigned short*>(
                        sH + ((m * 768 + f * 2) ^ ((m & 7) << 4))) = f2bf(v);
                }
            }
        }
    }
    __syncthreads();

    // ---------------- layer 2: out = h @ W2 + b2, wave w owns o in [w*32, w*32+32) ----
    f32x4 acc2[2][4];
    #pragma unroll
    for (int nt = 0; nt < 2; ++nt)
        #pragma unroll
        for (int mt = 0; mt < 4; ++mt) acc2[nt][mt] = {0.f, 0.f, 0.f, 0.f};

    #pragma unroll
    for (int kt = 0; kt < 12; ++kt) {
        bf16x8 Hf[4];
        #pragma unroll
        for (int mt = 0; mt < 4; ++mt) {
            const int m = mt * 16 + lr;
            Hf[mt] = *reinterpret_cast<const bf16x8*>(
                sH + ((m * 768 + kt * 64 + lg * 16) ^ ((m & 7) << 4)));
        }
        #pragma unroll
        for (int nt = 0; nt < 2; ++nt) {
            const bf16x8 Bf = *reinterpret_cast<const bf16x8*>(
                W2T + (w * 32 + nt * 16 + lr) * 384 + kt * 32 + lg * 8);
            #pragma unroll
            for (int mt = 0; mt < 4; ++mt)
                acc2[nt][mt] = __builtin_amdgcn_mfma_f32_16x16x32_bf16(Hf[mt], Bf, acc2[nt][mt], 0, 0, 0);
        }
    }
    // epilogue: bias + store fp32 out
    float* outp = out + (((long)((b << 14) + r0)) << 7);
    #pragma unroll
    for (int nt = 0; nt < 2; ++nt) {
        const int o = w * 32 + nt * 16 + lr;
        const float bias = b2[o];
        #pragma unroll
        for (int mt = 0; mt < 4; ++mt) {
            #pragma unroll
            for (int r = 0; r < 4; ++r) {
                const int m = mt * 16 + (lg << 2) + r;
                outp[m * 128 + o] = acc2[nt][mt][r] + bias;
            }
        }
    }
}

extern "C" void kernel_launch(void* const* d_in, const int* in_sizes, int n_in,
                              void* d_out, int out_size, void* d_ws, size_t ws_size,
                              hipStream_t stream) {
    const float* span = (const float*)d_in[0];
    const int*   rel  = (const int*)d_in[1];
    const float* W1   = (const float*)d_in[2];
    const float* b1   = (const float*)d_in[3];
    const float* W2   = (const float*)d_in[4];
    const float* b2   = (const float*)d_in[5];
    float* out = (float*)d_out;

    unsigned short* spanbf = (unsigned short*)d_ws;        // 2 MiB
    unsigned short* W1T = spanbf + B_ * S_ * H_;           // 192 KiB
    unsigned short* W2T = W1T + D_ * F_;                   // 96 KiB

    k_cvt_span<<<(B_ * S_ * H_ / 4) / 256, 256, 0, stream>>>(span, spanbf);
    k_t_w1<<<(D_ * F_) / 256, 256, 0, stream>>>(W1, W1T);
    k_t_w2<<<(F_ * H_) / 256, 256, 0, stream>>>(W2, W2T);
    k_main<<<(B_ * R_) / 64, 256, 81920, stream>>>(spanbf, rel, W1T, b1, W2T, b2, out);
}

// Round 2
// 93.263 us; speedup vs baseline: 1.3119x; 1.3119x over previous
//
#include <hip/hip_runtime.h>
#include <hip/hip_bf16.h>

typedef __attribute__((ext_vector_type(8))) short bf16x8;
typedef __attribute__((ext_vector_type(4))) float f32x4;

#define B_ 8
#define S_ 1024
#define R_ 16384
#define H_ 128
#define D_ 256     // input dim = 2H
#define F_ 384     // inter dim

__device__ __forceinline__ unsigned short f2bf(float x) {
    unsigned int u = __float_as_uint(x);
    u += 0x7FFF + ((u >> 16) & 1);   // round-to-nearest-even
    return (unsigned short)(u >> 16);
}

__global__ __launch_bounds__(256) void k_cvt_span(const float* __restrict__ in,
                                                  unsigned short* __restrict__ out) {
    int i = blockIdx.x * 256 + threadIdx.x;
    float4 v = reinterpret_cast<const float4*>(in)[i];
    ushort4 o;
    o.x = f2bf(v.x); o.y = f2bf(v.y); o.z = f2bf(v.z); o.w = f2bf(v.w);
    reinterpret_cast<ushort4*>(out)[i] = o;
}

__global__ __launch_bounds__(256) void k_t_w1(const float* __restrict__ W1,
                                              unsigned short* __restrict__ W1T) {
    int i = blockIdx.x * 256 + threadIdx.x;   // W1T[f][d] = W1[d][f]
    int d = i & 255, f = i >> 8;
    W1T[i] = f2bf(W1[d * F_ + f]);
}

__global__ __launch_bounds__(256) void k_t_w2(const float* __restrict__ W2,
                                              unsigned short* __restrict__ W2T) {
    int i = blockIdx.x * 256 + threadIdx.x;   // W2T[o][f] = W2[f][o]
    int o = i / F_, f = i - o * F_;
    W2T[i] = f2bf(W2[f * H_ + o]);
}

// 64 rows per block, 8 waves (512 threads).
// LDS: sA [64][256] bf16 (32 KiB, swizzled)  +  sH [64][384] bf16 (48 KiB, swizzled).
// Layer 1: wave w owns f in [w*48, w*48+48).  Layer 2: wave w owns o in [w*16, w*16+16).
// Both layers use SWAPPED mfma operands (W as A-operand) so D is transposed:
// lane holds 4 consecutive f (resp. o) values -> packed b64 LDS writes / float4 out.
__global__ __launch_bounds__(512, 4) void k_main(
    const unsigned short* __restrict__ spanbf,
    const int* __restrict__ rel_ids,
    const unsigned short* __restrict__ W1T,
    const float* __restrict__ b1,
    const unsigned short* __restrict__ W2T,
    const float* __restrict__ b2,
    float* __restrict__ out)
{
    extern __shared__ char smem[];
    char* sA = smem;              // [64][256] bf16, row stride 512 B, swizzled
    char* sH = smem + 32768;      // [64][384] bf16, row stride 768 B, swizzled

    const int tid = threadIdx.x;
    const int blk = blockIdx.x;           // 0..2047
    const int m0  = blk << 6;             // 64 rows per block
    const int b   = m0 >> 14;
    const int r0  = m0 & 16383;

    // ---------------- stage A: gathered rel_reps (bf16) ----------------
    {
        const int m = tid >> 3;               // 0..63 local row
        const int e = tid & 7;                // eighth of the 512-B row
        const int2 ids = reinterpret_cast<const int2*>(rel_ids)[(b << 14) + r0 + m];
        const int idx = (e < 4) ? ids.x : ids.y;
        const uint4* src = reinterpret_cast<const uint4*>(
            spanbf + (((b << 10) + idx) << 7) + ((e & 3) << 5));
        const int base = m * 512 + e * 64;
        const int swz = (m & 7) << 4;
        #pragma unroll
        for (int j = 0; j < 4; ++j) {
            uint4 v = src[j];
            *reinterpret_cast<uint4*>(sA + ((base + j * 16) ^ swz)) = v;
        }
    }
    __syncthreads();

    const int w  = tid >> 6;   // wave 0..7
    const int l  = tid & 63;
    const int lr = l & 15;
    const int lg = l >> 4;

    // ---------------- layer 1: h^T tiles = W1slice @ A^T ----------------
    {
        f32x4 acc[3][4];
        #pragma unroll
        for (int ft = 0; ft < 3; ++ft)
            #pragma unroll
            for (int mt = 0; mt < 4; ++mt) acc[ft][mt] = {0.f, 0.f, 0.f, 0.f};

        #pragma unroll 1
        for (int kp = 0; kp < 4; ++kp) {      // k-pairs: kt = kp*2 + k2
            bf16x8 Af[4][2];
            #pragma unroll
            for (int mt = 0; mt < 4; ++mt) {
                const int m = mt * 16 + lr;
                const int swz = (m & 7) << 4;
                #pragma unroll
                for (int k2 = 0; k2 < 2; ++k2) {
                    const int kt = kp * 2 + k2;
                    Af[mt][k2] = *reinterpret_cast<const bf16x8*>(
                        sA + ((m * 512 + kt * 64 + lg * 16) ^ swz));
                }
            }
            #pragma unroll
            for (int ft = 0; ft < 3; ++ft) {
                const unsigned short* wr = W1T + (w * 48 + ft * 16 + lr) * 256 + lg * 8;
                #pragma unroll
                for (int k2 = 0; k2 < 2; ++k2) {
                    const int kt = kp * 2 + k2;
                    bf16x8 Wf = *reinterpret_cast<const bf16x8*>(wr + kt * 32);
                    #pragma unroll
                    for (int mt = 0; mt < 4; ++mt)
                        acc[ft][mt] = __builtin_amdgcn_mfma_f32_16x16x32_bf16(
                            Wf, Af[mt][k2], acc[ft][mt], 0, 0, 0);
                }
            }
        }

        // epilogue: bias + relu + packed b64 store of h (lane holds 4 consecutive f)
        #pragma unroll
        for (int ft = 0; ft < 3; ++ft) {
            const int fb = w * 48 + ft * 16 + lg * 4;      // first of 4 consecutive f
            const float4 bias = *reinterpret_cast<const float4*>(b1 + fb);
            #pragma unroll
            for (int mt = 0; mt < 4; ++mt) {
                float v0 = fmaxf(acc[ft][mt][0] + bias.x, 0.0f);
                float v1 = fmaxf(acc[ft][mt][1] + bias.y, 0.0f);
                float v2 = fmaxf(acc[ft][mt][2] + bias.z, 0.0f);
                float v3 = fmaxf(acc[ft][mt][3] + bias.w, 0.0f);
                uint2 p;
                p.x = (unsigned)f2bf(v0) | ((unsigned)f2bf(v1) << 16);
                p.y = (unsigned)f2bf(v2) | ((unsigned)f2bf(v3) << 16);
                const int m = mt * 16 + lr;
                const int byte = m * 768 + fb * 2;
                *reinterpret_cast<uint2*>(sH + (byte ^ ((m & 7) << 4))) = p;
            }
        }
    }
    __syncthreads();

    // ---------------- layer 2: out^T tiles = W2slice @ h^T ----------------
    {
        bf16x8 W2f[12];
        const unsigned short* w2r = W2T + (w * 16 + lr) * 384 + lg * 8;
        #pragma unroll
        for (int kt = 0; kt < 12; ++kt)
            W2f[kt] = *reinterpret_cast<const bf16x8*>(w2r + kt * 32);

        f32x4 acc2[4];
        #pragma unroll
        for (int mt = 0; mt < 4; ++mt) acc2[mt] = {0.f, 0.f, 0.f, 0.f};

        #pragma unroll
        for (int kt = 0; kt < 12; ++kt) {
            #pragma unroll
            for (int mt = 0; mt < 4; ++mt) {
                const int m = mt * 16 + lr;
                bf16x8 Hf = *reinterpret_cast<const bf16x8*>(
                    sH + ((m * 768 + kt * 64 + lg * 16) ^ ((m & 7) << 4)));
                acc2[mt] = __builtin_amdgcn_mfma_f32_16x16x32_bf16(
                    W2f[kt], Hf, acc2[mt], 0, 0, 0);
            }
        }

        // epilogue: bias, stage fp32 tile into sA (reused), swizzled float4 writes
        const int ob = w * 16 + lg * 4;                    // 4 consecutive o per lane
        const float4 bias2 = *reinterpret_cast<const float4*>(b2 + ob);
        #pragma unroll
        for (int mt = 0; mt < 4; ++mt) {
            const int m = mt * 16 + lr;
            float4 v;
            v.x = acc2[mt][0] + bias2.x;
            v.y = acc2[mt][1] + bias2.y;
            v.z = acc2[mt][2] + bias2.z;
            v.w = acc2[mt][3] + bias2.w;
            *reinterpret_cast<float4*>(
                sA + ((m * 512 + ob * 4) ^ ((m & 7) << 4))) = v;
        }
    }
    __syncthreads();

    // ---------------- copy out: fully coalesced, 1 KiB contiguous per wave ----
    {
        const int c   = tid & 31;       // 16-B chunk within a 512-B row
        const int rsub = tid >> 5;      // 0..15
        #pragma unroll
        for (int pass = 0; pass < 4; ++pass) {
            const int m = pass * 16 + rsub;
            float4 v = *reinterpret_cast<const float4*>(
                sA + ((m * 512 + c * 16) ^ ((m & 7) << 4)));
            *reinterpret_cast<float4*>(out + ((long)(m0 + m)) * 128 + c * 4) = v;
        }
    }
}

extern "C" void kernel_launch(void* const* d_in, const int* in_sizes, int n_in,
                              void* d_out, int out_size, void* d_ws, size_t ws_size,
                              hipStream_t stream) {
    const float* span = (const float*)d_in[0];
    const int*   rel  = (const int*)d_in[1];
    const float* W1   = (const float*)d_in[2];
    const float* b1   = (const float*)d_in[3];
    const float* W2   = (const float*)d_in[4];
    const float* b2   = (const float*)d_in[5];
    float* out = (float*)d_out;

    unsigned short* spanbf = (unsigned short*)d_ws;        // 2 MiB
    unsigned short* W1T = spanbf + B_ * S_ * H_;           // 192 KiB
    unsigned short* W2T = W1T + D_ * F_;                   // 96 KiB

    k_cvt_span<<<(B_ * S_ * H_ / 4) / 256, 256, 0, stream>>>(span, spanbf);
    k_t_w1<<<(D_ * F_) / 256, 256, 0, stream>>>(W1, W1T);
    k_t_w2<<<(F_ * H_) / 256, 256, 0, stream>>>(W2, W2T);
    k_main<<<(B_ * R_) / 64, 512, 81920, stream>>>(spanbf, rel, W1T, b1, W2T, b2, out);
}